// Round 17
// baseline (3117.270 us; speedup 1.0000x reference)
//
#include <hip/hip_runtime.h>

// ---------------------------------------------------------------------------
// Seq2seq: 3-layer LSTM encoder + 3-layer LSTM decoder + dense vocab head
// B=32 T=128 V=32000 E=H=1024 L=3
// Round-16 config (3009 us proven) + gemm_bt upgraded to 2-phase pipelined
// staging (issue next tile's global_load_lds BEFORE current tile's MFMA so
// load latency hides under compute; double-buffered BK=32 LDS tiles).
// Encoder: persistent wavefront kernel (192 blocks, 8 waves = {h,x} x K-slice),
//   A-frags direct from chunked L3 exchange; wave0 poll + s_sleep + barrier.
// Decoder: per-layer persistent kernel (64 blocks, 4 K-split waves), chunked
//   L3 exchange; all-wave polling; flags monotonic across layers.
// Exchange coherence: sys-scope (sc0 sc1) ld/st bypass L1/L2, coherent at L3.
// ---------------------------------------------------------------------------

typedef __bf16 bf8 __attribute__((ext_vector_type(8)));
typedef float  f4  __attribute__((ext_vector_type(4)));

#define TLEN  128
#define HID   1024
#define G4    4096
#define VOC   32000
#define NBLK_SEQ 64

__device__ __forceinline__ ushort f2bf(float f) {
  unsigned u = __builtin_bit_cast(unsigned, f);
  u += 0x7fffu + ((u >> 16) & 1u);          // round-to-nearest-even
  return (ushort)(u >> 16);
}
__device__ __forceinline__ float sigmoidf_(float x) { return 1.f / (1.f + expf(-x)); }

// ---- system-scope (bypass L1+L2, coherent at L3) memory ops ----------------
__device__ __forceinline__ void ld16_sys(uint4& v, const void* p) {
  asm volatile("global_load_dwordx4 %0, %1, off sc0 sc1" : "=v"(v) : "v"(p));
}
__device__ __forceinline__ unsigned ld4_sys(const void* p) {
  unsigned v;
  asm volatile("global_load_dword %0, %1, off sc0 sc1\n\ts_waitcnt vmcnt(0)"
               : "=v"(v) : "v"(p) : "memory");
  return v;
}
__device__ __forceinline__ void ld4_sys3(unsigned& a, unsigned& b, unsigned& c,
                                         const void* pa, const void* pb, const void* pc) {
  asm volatile("global_load_dword %0, %3, off sc0 sc1\n\t"
               "global_load_dword %1, %4, off sc0 sc1\n\t"
               "global_load_dword %2, %5, off sc0 sc1\n\t"
               "s_waitcnt vmcnt(0)"
               : "=&v"(a), "=&v"(b), "=&v"(c)
               : "v"(pa), "v"(pb), "v"(pc) : "memory");
}
__device__ __forceinline__ void st4_sys(void* p, unsigned v) {
  asm volatile("global_store_dword %0, %1, off sc0 sc1" :: "v"(p), "v"(v) : "memory");
}
__device__ __forceinline__ void wait_vm0() {
  asm volatile("s_waitcnt vmcnt(0)" ::: "memory");
  __builtin_amdgcn_sched_barrier(0);
}

typedef const __attribute__((address_space(1))) void GvoidC;
typedef __attribute__((address_space(3))) void Lvoid;
__device__ __forceinline__ void g2l16(const void* g, void* l) {
  __builtin_amdgcn_global_load_lds((GvoidC*)g, (Lvoid*)l, 16, 0, 0);
}

// --- embedding gather: out[t*32+b][e] = bf16(emb[ids[b][t]][e]) -------------
__global__ __launch_bounds__(256) void embed_kernel(const int* __restrict__ ids,
    const float* __restrict__ emb, ushort* __restrict__ out) {
  int r = blockIdx.x;            // r = t*32 + b
  int b = r & 31, t = r >> 5;
  int id = ids[b * TLEN + t];
  const float4* src = (const float4*)(emb + (size_t)id * HID);
  float4 v = src[threadIdx.x];
  ushort4 o;
  o.x = f2bf(v.x); o.y = f2bf(v.y); o.z = f2bf(v.z); o.w = f2bf(v.w);
  *(ushort4*)(out + (size_t)r * HID + threadIdx.x * 4) = o;
}

// --- f32 [R][C] -> bf16 [C][R] tiled transpose ------------------------------
__global__ __launch_bounds__(256) void transpose_cvt(const float* __restrict__ W,
    ushort* __restrict__ Wt, int R, int C) {
  __shared__ float tile[32][33];
  int tx = threadIdx.x & 31, ty = threadIdx.x >> 5;   // ty 0..7
  int c0 = blockIdx.x * 32, r0 = blockIdx.y * 32;
  #pragma unroll
  for (int i = 0; i < 32; i += 8)
    tile[ty + i][tx] = W[(size_t)(r0 + ty + i) * C + c0 + tx];
  __syncthreads();
  #pragma unroll
  for (int i = 0; i < 32; i += 8)
    Wt[(size_t)(c0 + ty + i) * R + r0 + tx] = f2bf(tile[tx][ty + i]);
}

// --- bf16 MFMA GEMM: C[M][N] = A[M][K] @ Bt[N][K]^T + bias ------------------
// 128x128 tile; 2-PHASE PIPELINE: double-buffered BK=32 LDS tiles, next
// tile's 4 global_load_lds issued BEFORE current tile's ds_read+MFMA so the
// load latency hides under compute. XCD-aware bijective swizzle (nwg%8==0).
__global__ __launch_bounds__(256) void gemm_bt(const ushort* __restrict__ A,
    const ushort* __restrict__ Bt, const float* __restrict__ bias,
    float* __restrict__ C, int M, int N, int K, int permute) {
  __shared__ __align__(16) ushort lA[2 * 128 * 32];   // 2 bufs x 8 KiB
  __shared__ __align__(16) ushort lB[2 * 128 * 32];
  int tid = threadIdx.x;
  int lane = tid & 63, wave = tid >> 6;
  int nwg = gridDim.x * gridDim.y;
  int wg  = blockIdx.y * gridDim.x + blockIdx.x;
  int q   = nwg >> 3;
  int swg = (wg & 7) * q + (wg >> 3);          // bijective when nwg % 8 == 0
  int m0 = (swg / gridDim.x) * 128, n0 = (swg % gridDim.x) * 128;
  int wr = wave >> 1, wc = wave & 1;
  f4 zero = {0.f, 0.f, 0.f, 0.f};
  f4 acc[4][4];
  #pragma unroll
  for (int i = 0; i < 4; i++)
    #pragma unroll
    for (int j = 0; j < 4; j++) acc[i][j] = zero;

  const ushort* Ag = A  + (size_t)(m0 + wave * 32 + (lane >> 2)) * K + (lane & 3) * 8;
  const ushort* Bg = Bt + (size_t)(n0 + wave * 32 + (lane >> 2)) * K + (lane & 3) * 8;
  ushort* lAw = lA + wave * 1024;              // wave-uniform base in buf 0
  ushort* lBw = lB + wave * 1024;

  // prologue: stage tile kt=0 into buffer 0
  g2l16(Ag, lAw);
  g2l16(Ag + (size_t)16 * K, lAw + 512);
  g2l16(Bg, lBw);
  g2l16(Bg + (size_t)16 * K, lBw + 512);
  __syncthreads();                             // vmcnt(0) drain (prologue only)

  int cur = 0;
  for (int kt = 0; kt < K; kt += 32) {
    // issue NEXT tile's staging first (latency hides under MFMA below)
    if (kt + 32 < K) {
      ushort* lAn = lA + (cur ^ 1) * 4096 + wave * 1024;
      ushort* lBn = lB + (cur ^ 1) * 4096 + wave * 1024;
      g2l16(Ag + kt + 32, lAn);
      g2l16(Ag + (size_t)16 * K + kt + 32, lAn + 512);
      g2l16(Bg + kt + 32, lBn);
      g2l16(Bg + (size_t)16 * K + kt + 32, lBn + 512);
    }
    // compute current tile from buf[cur]
    const ushort* ab = lA + cur * 4096;
    const ushort* bb = lB + cur * 4096;
    bf8 aF[4], bF[4];
    #pragma unroll
    for (int i = 0; i < 4; i++)
      aF[i] = *(const bf8*)(ab + (wr * 64 + i * 16 + (lane & 15)) * 32 + (lane >> 4) * 8);
    #pragma unroll
    for (int j = 0; j < 4; j++)
      bF[j] = *(const bf8*)(bb + (wc * 64 + j * 16 + (lane & 15)) * 32 + (lane >> 4) * 8);
    #pragma unroll
    for (int i = 0; i < 4; i++)
      #pragma unroll
      for (int j = 0; j < 4; j++)
        acc[i][j] = __builtin_amdgcn_mfma_f32_16x16x32_bf16(aF[i], bF[j], acc[i][j], 0, 0, 0);
    __syncthreads();                           // drains (mostly-landed) loads
    cur ^= 1;
  }
  #pragma unroll
  for (int i = 0; i < 4; i++) {
    #pragma unroll
    for (int j = 0; j < 4; j++) {
      int col = n0 + wc * 64 + j * 16 + (lane & 15);
      float bv = bias ? bias[col] : 0.f;
      #pragma unroll
      for (int v = 0; v < 4; v++) {
        int row = m0 + wr * 64 + i * 16 + (lane >> 4) * 4 + v;
        int orow = permute ? ((row & 31) * TLEN + (row >> 5)) : row;
        C[(size_t)orow * N + col] = acc[i][j][v] + bv;
      }
    }
  }
}

// --- encoder wavefront: K-split waves, chunked L3 exchange (708 us proven) --
__global__ __launch_bounds__(512, 1) void enc_wave(
    const float*  __restrict__ Zpre,   // [128][32][4096] layer-0 pregates (incl bias)
    const ushort* __restrict__ WhT,    // 3 x [4096][1024]
    const ushort* __restrict__ WxT,    // 2 x [4096][1024] (layers 1,2 -> idx l-1)
    const float*  __restrict__ bE,     // [3][4096]
    ushort*       __restrict__ hxC,    // [3][2][64][32][16] chunked (pre-zeroed)
    float*        __restrict__ cSe,    // [3][32][1024] c state (pre-zeroed)
    ushort*       __restrict__ hS,     // [3][32][1024] final h out (linear)
    unsigned*     __restrict__ flags)  // 192 flags, stride 4 dwords
{
  const int bx = blockIdx.x;
  const int l = bx >> 6, jg = bx & 63;
  const int j0 = jg * 16;
  const int tid = threadIdx.x;
  const int lane = tid & 63, wave = tid >> 6;
  const int op = wave >> 2, ks = wave & 3;
  const int rr = tid >> 4, jj = tid & 15;           // combine: 512 thr = 32x16

  __shared__ float zp[8][4][32][17];   // [wave][gate][row][col+pad]

  float cc = cSe[(size_t)l * 32768 + rr * HID + j0 + jj];
  float bias4[4];
  #pragma unroll
  for (int g = 0; g < 4; g++)
    bias4[g] = bE[l * G4 + g * HID + j0 + jj];

  const bool mfma_on = (l > 0) || (op == 0);
  bf8 bw[4][8];
  if (mfma_on) {
    const ushort* Wb = op ? (WxT + (size_t)(l - 1) * G4 * HID)
                          : (WhT + (size_t)l * G4 * HID);
    #pragma unroll
    for (int g = 0; g < 4; g++) {
      const ushort* Bp = Wb + (size_t)(g * HID + j0 + (lane & 15)) * HID
                       + ks * 256 + (lane >> 4) * 8;
      #pragma unroll
      for (int kk = 0; kk < 8; kk++)
        bw[g][kk] = *(const bf8*)(Bp + kk * 32);
    }
  }

  const int r0 = lane & 15, r1 = r0 + 16;
  const int lk = lane >> 4;
  const int aoff0 = ks * 8192 + (lk >> 1) * 512 + r0 * 16 + (lk & 1) * 8;
  const int aoff1 = ks * 8192 + (lk >> 1) * 512 + r1 * 16 + (lk & 1) * 8;

  float zv4[4], zn4[4];
  if (l == 0) {
    #pragma unroll
    for (int g = 0; g < 4; g++)
      zv4[g] = Zpre[(size_t)rr * G4 + g * HID + j0 + jj];
  }

  for (int w = 0; w < 130; ++w) {
    if (w > 0) {
      if (wave == 0) {
        for (;;) {
          unsigned a, b, c;
          ld4_sys3(a, b, c, flags + lane * 4, flags + (64 + lane) * 4,
                   flags + (128 + lane) * 4);
          if (!__ballot(a < (unsigned)w || b < (unsigned)w || c < (unsigned)w)) break;
          __builtin_amdgcn_s_sleep(1);
        }
      }
      __syncthreads();
    }
    const int t = w - l;
    if (t >= 0 && t < TLEN) {
      // ---- A-fragments direct from chunked L3 exchange ----
      uint4 ha0[8], ha1[8];
      if (mfma_on) {
        const ushort* src = (op == 0)
          ? hxC + ((size_t)l * 2 + ((t - 1) & 1)) * 32768          // own h_{t-1}
          : hxC + ((size_t)(l - 1) * 2 + (t & 1)) * 32768;         // below's y_t
        #pragma unroll
        for (int kk = 0; kk < 8; kk++) {
          ld16_sys(ha0[kk], src + aoff0 + kk * 1024);
          ld16_sys(ha1[kk], src + aoff1 + kk * 1024);
        }
        wait_vm0();
      }

      if (l == 0 && t + 1 < TLEN) {
        const float* Ztn = Zpre + (size_t)(t + 1) * 32 * G4;
        #pragma unroll
        for (int g = 0; g < 4; g++)
          zn4[g] = Ztn[(size_t)rr * G4 + g * HID + j0 + jj];
      }

      if (mfma_on) {
        f4 acc0[4], acc1[4];
        #pragma unroll
        for (int g = 0; g < 4; g++) { acc0[g] = (f4){0,0,0,0}; acc1[g] = (f4){0,0,0,0}; }
        #pragma unroll
        for (int kk = 0; kk < 8; kk++) {
          bf8 a0 = __builtin_bit_cast(bf8, ha0[kk]);
          bf8 a1 = __builtin_bit_cast(bf8, ha1[kk]);
          #pragma unroll
          for (int g = 0; g < 4; g++) {
            acc0[g] = __builtin_amdgcn_mfma_f32_16x16x32_bf16(a0, bw[g][kk], acc0[g], 0, 0, 0);
            acc1[g] = __builtin_amdgcn_mfma_f32_16x16x32_bf16(a1, bw[g][kk], acc1[g], 0, 0, 0);
          }
        }
        #pragma unroll
        for (int g = 0; g < 4; g++)
          #pragma unroll
          for (int v = 0; v < 4; v++) {
            zp[wave][g][(lane >> 4) * 4 + v][lane & 15]      = acc0[g][v];
            zp[wave][g][16 + (lane >> 4) * 4 + v][lane & 15] = acc1[g][v];
          }
      }
      __syncthreads();

      // ---- combine + gates (thread owns row rr, col j0+jj) ----
      float z[4];
      #pragma unroll
      for (int g = 0; g < 4; g++) {
        float s = zp[0][g][rr][jj] + zp[1][g][rr][jj]
                + zp[2][g][rr][jj] + zp[3][g][rr][jj];
        if (l > 0)
          s += zp[4][g][rr][jj] + zp[5][g][rr][jj]
             + zp[6][g][rr][jj] + zp[7][g][rr][jj] + bias4[g];
        else
          s += zv4[g];
        z[g] = s;
      }
      if (l == 0) {
        #pragma unroll
        for (int g = 0; g < 4; g++) zv4[g] = zn4[g];
      }
      float ig = sigmoidf_(z[0]), fg = sigmoidf_(z[1]);
      float gv = tanhf(z[2]),     og = sigmoidf_(z[3]);
      cc = fg * cc + ig * gv;
      float hv = og * tanhf(cc);
      ushort hb = f2bf(hv);
      // chunked publish: even-jj threads store packed 4B (full-line pattern)
      unsigned u = (unsigned)hb;
      unsigned nb = __shfl_xor(u, 1);
      if ((jj & 1) == 0)
        st4_sys(hxC + ((size_t)l * 2 + (t & 1)) * 32768 + jg * 512 + rr * 16 + jj,
                u | (nb << 16));
      if (t == TLEN - 1) {
        hS [(size_t)l * 32768 + rr * HID + j0 + jj] = hb;
        cSe[(size_t)l * 32768 + rr * HID + j0 + jj] = cc;
      }
      wait_vm0();
    }
    __syncthreads();
    if (tid == 0) st4_sys(flags + bx * 4, (unsigned)(w + 1));
  }
}

// --- decoder per-layer persistent recurrence --------------------------------
// Flags monotonic across layers: layer l uses fbase = l*TLEN; h0 for layers
// 1,2 is already in the correct parity slot (prev layer's last publish).
__global__ __launch_bounds__(256, 1) void lstm_seq(
    const float*  __restrict__ Zpre,   // [TLEN][32][4096] (incl bias)
    const ushort* __restrict__ Wht,    // [4096][1024]
    float*        __restrict__ cS,     // [32][1024] c state in/out
    ushort*       __restrict__ yout,   // [TLEN][32][1024] linear out
    ushort*       __restrict__ hx,     // [2][64][32][16] chunked exchange
    unsigned*     __restrict__ flags,  // 64 flags, stride 4 dwords
    unsigned fbase)
{
  const int jg = blockIdx.x;
  const int j0 = jg * 16;
  const int tid = threadIdx.x;
  const int lane = tid & 63, wave = tid >> 6;
  const int rr = tid >> 3, cp = tid & 7;

  __shared__ float zp[4][4][32][17];   // [k-slice wave][gate][row][col+pad]

  float2 cc = *(const float2*)(cS + (size_t)rr * HID + j0 + 2 * cp);

  bf8 bw[4][8];
  #pragma unroll
  for (int g = 0; g < 4; g++) {
    const ushort* Bp = Wht + (size_t)(g * HID + j0 + (lane & 15)) * HID
                     + wave * 256 + (lane >> 4) * 8;
    #pragma unroll
    for (int kk = 0; kk < 8; kk++)
      bw[g][kk] = *(const bf8*)(Bp + kk * 32);
  }

  const int r0 = lane & 15, r1 = r0 + 16;
  const int lk = lane >> 4;
  const int aoff0 = wave * 8192 + (lk >> 1) * 512 + r0 * 16 + (lk & 1) * 8;
  const int aoff1 = wave * 8192 + (lk >> 1) * 512 + r1 * 16 + (lk & 1) * 8;

  float2 zv[4], zn[4];
  #pragma unroll
  for (int g = 0; g < 4; g++)
    zv[g] = *(const float2*)(Zpre + (size_t)rr * G4 + g * HID + j0 + 2 * cp);

  for (int t = 0; t < TLEN; ++t) {
    // all 4 waves poll independently; no barrier afterward (256 streams: ok)
    if (t > 0) {
      const unsigned* fp = flags + lane * 4;
      const unsigned want = fbase + (unsigned)t;
      while (__ballot(ld4_sys(fp) < want)) {}
    }
    const ushort* hsrc = hx + ((t + 1) & 1) * 32768;
    uint4 ha0[8], ha1[8];
    #pragma unroll
    for (int kk = 0; kk < 8; kk++) {
      ld16_sys(ha0[kk], hsrc + aoff0 + kk * 1024);
      ld16_sys(ha1[kk], hsrc + aoff1 + kk * 1024);
    }
    wait_vm0();

    if (t + 1 < TLEN) {
      const float* Ztn = Zpre + (size_t)(t + 1) * 32 * G4;
      #pragma unroll
      for (int g = 0; g < 4; g++)
        zn[g] = *(const float2*)(Ztn + (size_t)rr * G4 + g * HID + j0 + 2 * cp);
    }

    f4 acc0[4], acc1[4];
    #pragma unroll
    for (int g = 0; g < 4; g++) { acc0[g] = (f4){0,0,0,0}; acc1[g] = (f4){0,0,0,0}; }
    #pragma unroll
    for (int kk = 0; kk < 8; kk++) {
      bf8 a0 = __builtin_bit_cast(bf8, ha0[kk]);
      bf8 a1 = __builtin_bit_cast(bf8, ha1[kk]);
      #pragma unroll
      for (int g = 0; g < 4; g++) {
        acc0[g] = __builtin_amdgcn_mfma_f32_16x16x32_bf16(a0, bw[g][kk], acc0[g], 0, 0, 0);
        acc1[g] = __builtin_amdgcn_mfma_f32_16x16x32_bf16(a1, bw[g][kk], acc1[g], 0, 0, 0);
      }
    }
    #pragma unroll
    for (int g = 0; g < 4; g++)
      #pragma unroll
      for (int v = 0; v < 4; v++) {
        zp[wave][g][(lane >> 4) * 4 + v][lane & 15]      = acc0[g][v];
        zp[wave][g][16 + (lane >> 4) * 4 + v][lane & 15] = acc1[g][v];
      }
    __syncthreads();

    float zx[4], zy[4];
    #pragma unroll
    for (int g = 0; g < 4; g++) {
      zx[g] = zv[g].x + zp[0][g][rr][2 * cp]     + zp[1][g][rr][2 * cp]
                      + zp[2][g][rr][2 * cp]     + zp[3][g][rr][2 * cp];
      zy[g] = zv[g].y + zp[0][g][rr][2 * cp + 1] + zp[1][g][rr][2 * cp + 1]
                      + zp[2][g][rr][2 * cp + 1] + zp[3][g][rr][2 * cp + 1];
    }
    cc.x = sigmoidf_(zx[1]) * cc.x + sigmoidf_(zx[0]) * tanhf(zx[2]);
    cc.y = sigmoidf_(zy[1]) * cc.y + sigmoidf_(zy[0]) * tanhf(zy[2]);
    float hv0 = sigmoidf_(zx[3]) * tanhf(cc.x);
    float hv1 = sigmoidf_(zy[3]) * tanhf(cc.y);
    unsigned packed = (unsigned)f2bf(hv0) | ((unsigned)f2bf(hv1) << 16);
    *(unsigned*)(yout + (size_t)t * 32768 + rr * HID + j0 + 2 * cp) = packed;
    st4_sys(hx + (size_t)(t & 1) * 32768 + jg * 512 + rr * 16 + 2 * cp, packed);
    #pragma unroll
    for (int g = 0; g < 4; g++) zv[g] = zn[g];

    wait_vm0();
    __syncthreads();
    if (tid == 0) st4_sys(flags + jg * 4, fbase + (unsigned)(t + 1));
  }
  *(float2*)(cS + (size_t)rr * HID + j0 + 2 * cp) = cc;
}

// --- prep kernels -----------------------------------------------------------
__global__ __launch_bounds__(256) void prep_enc(ushort* hxC, float* cSe,
                                                unsigned* flags) {
  int i = blockIdx.x * 256 + threadIdx.x;      // 768 blocks * 256 = 196608
  hxC[i] = 0;
  if (i < 98304) cSe[i] = 0.f;
  if (i < 192)   flags[i * 4] = 0;
}
// enc final state -> chunk layout into hx[1]; c copy; flags zeroed (once)
__global__ __launch_bounds__(256) void prep_dec0(const ushort* __restrict__ hS2,
                                                 const float* __restrict__ cSe2,
                                                 float* cS, ushort* hx,
                                                 unsigned* flags) {
  int i = blockIdx.x * 256 + threadIdx.x;      // 128 blocks * 256 = 32768
  int row = i >> 10, col = i & 1023;
  hx[32768 + (col >> 4) * 512 + row * 16 + (col & 15)] = hS2[i];
  cS[i] = cSe2[i];
  if (i < NBLK_SEQ) flags[i * 4] = 0;
}

// ---------------------------------------------------------------------------
extern "C" void kernel_launch(void* const* d_in, const int* in_sizes, int n_in,
                              void* d_out, int out_size, void* d_ws, size_t ws_size,
                              hipStream_t stream) {
  const int*   enc_ids = (const int*)d_in[0];
  const int*   dec_ids = (const int*)d_in[1];
  const float* emb     = (const float*)d_in[2];
  const float* Wx_enc  = (const float*)d_in[3];
  const float* Wh_enc  = (const float*)d_in[4];
  const float* b_enc   = (const float*)d_in[5];
  const float* Wx_dec  = (const float*)d_in[6];
  const float* Wh_dec  = (const float*)d_in[7];
  const float* b_dec   = (const float*)d_in[8];
  const float* dense_W = (const float*)d_in[9];
  const float* dense_b = (const float*)d_in[10];
  float* out = (float*)d_out;

  // ---- d_ws layout (proven footprint) ----
  char* ws = (char*)d_ws;
  const size_t SZ_BUF = (size_t)4096 * 1024 * 2;   // 8 MiB
  ushort*   bufA   = (ushort*)(ws);
  ushort*   bufB   = (ushort*)(ws + SZ_BUF);
  ushort*   Wxt    = (ushort*)(ws + 2 * SZ_BUF);
  ushort*   Wht    = (ushort*)(ws + 3 * SZ_BUF);
  ushort*   dWt    = (ushort*)(ws + 4 * SZ_BUF);   // VOC*1024*2 B
  char*     p2     = ws + 4 * SZ_BUF + (size_t)VOC * 1024 * 2;
  float*    cS     = (float*)(p2 + (size_t)32 * 1024 * 2);   // 128 KiB
  unsigned* flags  = (unsigned*)(p2 + (size_t)32 * 1024 * 2 + (size_t)32 * 1024 * 4);

  // ---- d_out dead-region scratch (500 MB buffer, dense head writes last) --
  char* ob = (char*)d_out;
  float*    Zpre   = out;                                        // [0, 64 MiB)
  ushort*   WhTe   = (ushort*)(ob + (size_t)64  * 1024 * 1024);  // 3 x 8 MiB
  ushort*   WxTe   = (ushort*)(ob + (size_t)88  * 1024 * 1024);  // 2 x 8 MiB
  char*     st     = ob + (size_t)112 * 1024 * 1024;
  ushort*   hxC    = (ushort*)st;                                // 384 KiB chunked
  float*    cSe    = (float*)(st + 393216);                      // 384 KiB
  ushort*   hS     = (ushort*)(st + 786432);                     // 192 KiB
  unsigned* flags2 = (unsigned*)(st + 983040);                   // 3 KiB
  ushort*   hxD    = (ushort*)(ob + (size_t)120 * 1024 * 1024);  // 128 KiB chunked
  const size_t WSTRIDE = (size_t)G4 * HID;                       // elements

  transpose_cvt<<<dim3(VOC / 32, 1024 / 32), 256, 0, stream>>>(dense_W, dWt, 1024, VOC);

  // ---------------- encoder ----------------
  embed_kernel<<<4096, 256, 0, stream>>>(enc_ids, emb, bufA);
  transpose_cvt<<<dim3(G4 / 32, 32), 256, 0, stream>>>(Wx_enc, Wxt, 1024, G4);
  gemm_bt<<<dim3(G4 / 128, 4096 / 128), 256, 0, stream>>>(bufA, Wxt, b_enc,
                                                          Zpre, 4096, G4, 1024, 0);
  for (int l = 0; l < 3; l++)
    transpose_cvt<<<dim3(G4 / 32, 32), 256, 0, stream>>>(Wh_enc + (size_t)l * 1024 * G4,
                                                         WhTe + l * WSTRIDE, 1024, G4);
  for (int l = 1; l < 3; l++)
    transpose_cvt<<<dim3(G4 / 32, 32), 256, 0, stream>>>(Wx_enc + (size_t)l * 1024 * G4,
                                                         WxTe + (l - 1) * WSTRIDE, 1024, G4);
  prep_enc<<<768, 256, 0, stream>>>(hxC, cSe, flags2);
  enc_wave<<<192, 512, 0, stream>>>(Zpre, WhTe, WxTe, b_enc, hxC, cSe, hS, flags2);

  // ---------------- decoder (serial chaining -> per-layer) ----------------
  embed_kernel<<<4096, 256, 0, stream>>>(dec_ids, emb, bufA);
  ushort* cur = bufA; ushort* oth = bufB;
  for (int l = 0; l < 3; l++) {
    transpose_cvt<<<dim3(G4 / 32, 32), 256, 0, stream>>>(Wx_dec + (size_t)l * 1024 * G4, Wxt, 1024, G4);
    transpose_cvt<<<dim3(G4 / 32, 32), 256, 0, stream>>>(Wh_dec + (size_t)l * 1024 * G4, Wht, 1024, G4);
    gemm_bt<<<dim3(G4 / 128, 4096 / 128), 256, 0, stream>>>(cur, Wxt, b_dec + (size_t)l * G4,
                                                            Zpre, 4096, G4, 1024, 0);
    if (l == 0)
      prep_dec0<<<128, 256, 0, stream>>>(hS + 2 * 32768, cSe + 2 * 32768, cS, hxD, flags);
    // layers 1,2: h0 already in hxD parity-1 slot; c chains in cS; flags continue
    lstm_seq<<<NBLK_SEQ, 256, 0, stream>>>(Zpre, Wht, cS, oth, hxD, flags,
                                           (unsigned)(l * TLEN));
    ushort* tmp = cur; cur = oth; oth = tmp;
  }

  // ---------------- dense head: logits[b][t][v] ----------------
  gemm_bt<<<dim3(VOC / 128, 4096 / 128), 256, 0, stream>>>(cur, dWt, dense_b, out,
                                                           4096, VOC, 1024, 1);
}

// Round 18
// 3006.837 us; speedup vs baseline: 1.0367x; 1.0367x over previous
//
#include <hip/hip_runtime.h>

// ---------------------------------------------------------------------------
// Seq2seq: 3-layer LSTM encoder + 3-layer LSTM decoder + dense vocab head
// B=32 T=128 V=32000 E=H=1024 L=3
// ROUND-16 CONFIGURATION (best measured: 3009 us). Round-17's 2-phase GEMM
// pipelining reverted: same barrier count as BK=64, but only 16 MFMA between
// load-issue and the vmcnt(0) drain -> latency not hidden, and the reorder
// defeated the compiler's own scheduling (learn_hip m131-m141 lesson).
// Encoder: persistent wavefront kernel (192 blocks, 8 waves = {h,x} x K-slice),
//   A-frags direct from chunked L3 exchange; wave0 poll + s_sleep + barrier.
// Decoder: per-layer persistent kernel (64 blocks, 4 K-split waves), chunked
//   L3 exchange; all-wave polling; flags monotonic across layers.
// Exchange coherence: sys-scope (sc0 sc1) ld/st bypass L1/L2, coherent at L3.
// GEMMs: 128x128 tile, BK=64 dual 32-wide LDS buffers; XCD-aware bijective
//   block swizzle (all grids %8 == 0).
// ---------------------------------------------------------------------------

typedef __bf16 bf8 __attribute__((ext_vector_type(8)));
typedef float  f4  __attribute__((ext_vector_type(4)));

#define TLEN  128
#define HID   1024
#define G4    4096
#define VOC   32000
#define NBLK_SEQ 64

__device__ __forceinline__ ushort f2bf(float f) {
  unsigned u = __builtin_bit_cast(unsigned, f);
  u += 0x7fffu + ((u >> 16) & 1u);          // round-to-nearest-even
  return (ushort)(u >> 16);
}
__device__ __forceinline__ float sigmoidf_(float x) { return 1.f / (1.f + expf(-x)); }

// ---- system-scope (bypass L1+L2, coherent at L3) memory ops ----------------
__device__ __forceinline__ void ld16_sys(uint4& v, const void* p) {
  asm volatile("global_load_dwordx4 %0, %1, off sc0 sc1" : "=v"(v) : "v"(p));
}
__device__ __forceinline__ unsigned ld4_sys(const void* p) {
  unsigned v;
  asm volatile("global_load_dword %0, %1, off sc0 sc1\n\ts_waitcnt vmcnt(0)"
               : "=v"(v) : "v"(p) : "memory");
  return v;
}
__device__ __forceinline__ void ld4_sys3(unsigned& a, unsigned& b, unsigned& c,
                                         const void* pa, const void* pb, const void* pc) {
  asm volatile("global_load_dword %0, %3, off sc0 sc1\n\t"
               "global_load_dword %1, %4, off sc0 sc1\n\t"
               "global_load_dword %2, %5, off sc0 sc1\n\t"
               "s_waitcnt vmcnt(0)"
               : "=&v"(a), "=&v"(b), "=&v"(c)
               : "v"(pa), "v"(pb), "v"(pc) : "memory");
}
__device__ __forceinline__ void st4_sys(void* p, unsigned v) {
  asm volatile("global_store_dword %0, %1, off sc0 sc1" :: "v"(p), "v"(v) : "memory");
}
__device__ __forceinline__ void wait_vm0() {
  asm volatile("s_waitcnt vmcnt(0)" ::: "memory");
  __builtin_amdgcn_sched_barrier(0);
}

typedef const __attribute__((address_space(1))) void GvoidC;
typedef __attribute__((address_space(3))) void Lvoid;
__device__ __forceinline__ void g2l16(const void* g, void* l) {
  __builtin_amdgcn_global_load_lds((GvoidC*)g, (Lvoid*)l, 16, 0, 0);
}

// --- embedding gather: out[t*32+b][e] = bf16(emb[ids[b][t]][e]) -------------
__global__ __launch_bounds__(256) void embed_kernel(const int* __restrict__ ids,
    const float* __restrict__ emb, ushort* __restrict__ out) {
  int r = blockIdx.x;            // r = t*32 + b
  int b = r & 31, t = r >> 5;
  int id = ids[b * TLEN + t];
  const float4* src = (const float4*)(emb + (size_t)id * HID);
  float4 v = src[threadIdx.x];
  ushort4 o;
  o.x = f2bf(v.x); o.y = f2bf(v.y); o.z = f2bf(v.z); o.w = f2bf(v.w);
  *(ushort4*)(out + (size_t)r * HID + threadIdx.x * 4) = o;
}

// --- f32 [R][C] -> bf16 [C][R] tiled transpose ------------------------------
__global__ __launch_bounds__(256) void transpose_cvt(const float* __restrict__ W,
    ushort* __restrict__ Wt, int R, int C) {
  __shared__ float tile[32][33];
  int tx = threadIdx.x & 31, ty = threadIdx.x >> 5;   // ty 0..7
  int c0 = blockIdx.x * 32, r0 = blockIdx.y * 32;
  #pragma unroll
  for (int i = 0; i < 32; i += 8)
    tile[ty + i][tx] = W[(size_t)(r0 + ty + i) * C + c0 + tx];
  __syncthreads();
  #pragma unroll
  for (int i = 0; i < 32; i += 8)
    Wt[(size_t)(c0 + ty + i) * R + r0 + tx] = f2bf(tile[tx][ty + i]);
}

// --- bf16 MFMA GEMM: C[M][N] = A[M][K] @ Bt[N][K]^T + bias ------------------
// 128x128 tile, BK=64 via two 32-wide LDS buffers (one barrier pair / 64-K).
// XCD-aware bijective swizzle (requires nwg % 8 == 0; grids 1024/1024/8000).
__global__ __launch_bounds__(256) void gemm_bt(const ushort* __restrict__ A,
    const ushort* __restrict__ Bt, const float* __restrict__ bias,
    float* __restrict__ C, int M, int N, int K, int permute) {
  __shared__ __align__(16) ushort lA[2 * 128 * 32];
  __shared__ __align__(16) ushort lB[2 * 128 * 32];
  int tid = threadIdx.x;
  int lane = tid & 63, wave = tid >> 6;
  int nwg = gridDim.x * gridDim.y;
  int wg  = blockIdx.y * gridDim.x + blockIdx.x;
  int q   = nwg >> 3;
  int swg = (wg & 7) * q + (wg >> 3);          // bijective when nwg % 8 == 0
  int m0 = (swg / gridDim.x) * 128, n0 = (swg % gridDim.x) * 128;
  int wr = wave >> 1, wc = wave & 1;
  f4 zero = {0.f, 0.f, 0.f, 0.f};
  f4 acc[4][4];
  #pragma unroll
  for (int i = 0; i < 4; i++)
    #pragma unroll
    for (int j = 0; j < 4; j++) acc[i][j] = zero;

  const ushort* Ag = A  + (size_t)(m0 + wave * 32 + (lane >> 2)) * K + (lane & 3) * 8;
  const ushort* Bg = Bt + (size_t)(n0 + wave * 32 + (lane >> 2)) * K + (lane & 3) * 8;
  ushort* lApa = lA + wave * 1024;            // buf 0, rows wave*32..
  ushort* lApb = lA + 4096 + wave * 1024;     // buf 1
  ushort* lBpa = lB + wave * 1024;
  ushort* lBpb = lB + 4096 + wave * 1024;

  for (int kt = 0; kt < K; kt += 64) {
    g2l16(Ag + kt,                    lApa);
    g2l16(Ag + (size_t)16 * K + kt,       lApa + 512);
    g2l16(Ag + kt + 32,               lApb);
    g2l16(Ag + (size_t)16 * K + kt + 32,  lApb + 512);
    g2l16(Bg + kt,                    lBpa);
    g2l16(Bg + (size_t)16 * K + kt,       lBpa + 512);
    g2l16(Bg + kt + 32,               lBpb);
    g2l16(Bg + (size_t)16 * K + kt + 32,  lBpb + 512);
    __syncthreads();
    #pragma unroll
    for (int h = 0; h < 2; h++) {
      const ushort* ab = lA + h * 4096;
      const ushort* bb = lB + h * 4096;
      bf8 aF[4], bF[4];
      #pragma unroll
      for (int i = 0; i < 4; i++)
        aF[i] = *(const bf8*)(ab + (wr * 64 + i * 16 + (lane & 15)) * 32 + (lane >> 4) * 8);
      #pragma unroll
      for (int j = 0; j < 4; j++)
        bF[j] = *(const bf8*)(bb + (wc * 64 + j * 16 + (lane & 15)) * 32 + (lane >> 4) * 8);
      #pragma unroll
      for (int i = 0; i < 4; i++)
        #pragma unroll
        for (int j = 0; j < 4; j++)
          acc[i][j] = __builtin_amdgcn_mfma_f32_16x16x32_bf16(aF[i], bF[j], acc[i][j], 0, 0, 0);
    }
    __syncthreads();
  }
  #pragma unroll
  for (int i = 0; i < 4; i++) {
    #pragma unroll
    for (int j = 0; j < 4; j++) {
      int col = n0 + wc * 64 + j * 16 + (lane & 15);
      float bv = bias ? bias[col] : 0.f;
      #pragma unroll
      for (int v = 0; v < 4; v++) {
        int row = m0 + wr * 64 + i * 16 + (lane >> 4) * 4 + v;
        int orow = permute ? ((row & 31) * TLEN + (row >> 5)) : row;
        C[(size_t)orow * N + col] = acc[i][j][v] + bv;
      }
    }
  }
}

// --- encoder wavefront: K-split waves, chunked L3 exchange (708 us proven) --
__global__ __launch_bounds__(512, 1) void enc_wave(
    const float*  __restrict__ Zpre,   // [128][32][4096] layer-0 pregates (incl bias)
    const ushort* __restrict__ WhT,    // 3 x [4096][1024]
    const ushort* __restrict__ WxT,    // 2 x [4096][1024] (layers 1,2 -> idx l-1)
    const float*  __restrict__ bE,     // [3][4096]
    ushort*       __restrict__ hxC,    // [3][2][64][32][16] chunked (pre-zeroed)
    float*        __restrict__ cSe,    // [3][32][1024] c state (pre-zeroed)
    ushort*       __restrict__ hS,     // [3][32][1024] final h out (linear)
    unsigned*     __restrict__ flags)  // 192 flags, stride 4 dwords
{
  const int bx = blockIdx.x;
  const int l = bx >> 6, jg = bx & 63;
  const int j0 = jg * 16;
  const int tid = threadIdx.x;
  const int lane = tid & 63, wave = tid >> 6;
  const int op = wave >> 2, ks = wave & 3;
  const int rr = tid >> 4, jj = tid & 15;           // combine: 512 thr = 32x16

  __shared__ float zp[8][4][32][17];   // [wave][gate][row][col+pad]

  float cc = cSe[(size_t)l * 32768 + rr * HID + j0 + jj];
  float bias4[4];
  #pragma unroll
  for (int g = 0; g < 4; g++)
    bias4[g] = bE[l * G4 + g * HID + j0 + jj];

  const bool mfma_on = (l > 0) || (op == 0);
  bf8 bw[4][8];
  if (mfma_on) {
    const ushort* Wb = op ? (WxT + (size_t)(l - 1) * G4 * HID)
                          : (WhT + (size_t)l * G4 * HID);
    #pragma unroll
    for (int g = 0; g < 4; g++) {
      const ushort* Bp = Wb + (size_t)(g * HID + j0 + (lane & 15)) * HID
                       + ks * 256 + (lane >> 4) * 8;
      #pragma unroll
      for (int kk = 0; kk < 8; kk++)
        bw[g][kk] = *(const bf8*)(Bp + kk * 32);
    }
  }

  const int r0 = lane & 15, r1 = r0 + 16;
  const int lk = lane >> 4;
  const int aoff0 = ks * 8192 + (lk >> 1) * 512 + r0 * 16 + (lk & 1) * 8;
  const int aoff1 = ks * 8192 + (lk >> 1) * 512 + r1 * 16 + (lk & 1) * 8;

  float zv4[4], zn4[4];
  if (l == 0) {
    #pragma unroll
    for (int g = 0; g < 4; g++)
      zv4[g] = Zpre[(size_t)rr * G4 + g * HID + j0 + jj];
  }

  for (int w = 0; w < 130; ++w) {
    if (w > 0) {
      if (wave == 0) {
        for (;;) {
          unsigned a, b, c;
          ld4_sys3(a, b, c, flags + lane * 4, flags + (64 + lane) * 4,
                   flags + (128 + lane) * 4);
          if (!__ballot(a < (unsigned)w || b < (unsigned)w || c < (unsigned)w)) break;
          __builtin_amdgcn_s_sleep(1);
        }
      }
      __syncthreads();
    }
    const int t = w - l;
    if (t >= 0 && t < TLEN) {
      // ---- A-fragments direct from chunked L3 exchange ----
      uint4 ha0[8], ha1[8];
      if (mfma_on) {
        const ushort* src = (op == 0)
          ? hxC + ((size_t)l * 2 + ((t - 1) & 1)) * 32768          // own h_{t-1}
          : hxC + ((size_t)(l - 1) * 2 + (t & 1)) * 32768;         // below's y_t
        #pragma unroll
        for (int kk = 0; kk < 8; kk++) {
          ld16_sys(ha0[kk], src + aoff0 + kk * 1024);
          ld16_sys(ha1[kk], src + aoff1 + kk * 1024);
        }
        wait_vm0();
      }

      if (l == 0 && t + 1 < TLEN) {
        const float* Ztn = Zpre + (size_t)(t + 1) * 32 * G4;
        #pragma unroll
        for (int g = 0; g < 4; g++)
          zn4[g] = Ztn[(size_t)rr * G4 + g * HID + j0 + jj];
      }

      if (mfma_on) {
        f4 acc0[4], acc1[4];
        #pragma unroll
        for (int g = 0; g < 4; g++) { acc0[g] = (f4){0,0,0,0}; acc1[g] = (f4){0,0,0,0}; }
        #pragma unroll
        for (int kk = 0; kk < 8; kk++) {
          bf8 a0 = __builtin_bit_cast(bf8, ha0[kk]);
          bf8 a1 = __builtin_bit_cast(bf8, ha1[kk]);
          #pragma unroll
          for (int g = 0; g < 4; g++) {
            acc0[g] = __builtin_amdgcn_mfma_f32_16x16x32_bf16(a0, bw[g][kk], acc0[g], 0, 0, 0);
            acc1[g] = __builtin_amdgcn_mfma_f32_16x16x32_bf16(a1, bw[g][kk], acc1[g], 0, 0, 0);
          }
        }
        #pragma unroll
        for (int g = 0; g < 4; g++)
          #pragma unroll
          for (int v = 0; v < 4; v++) {
            zp[wave][g][(lane >> 4) * 4 + v][lane & 15]      = acc0[g][v];
            zp[wave][g][16 + (lane >> 4) * 4 + v][lane & 15] = acc1[g][v];
          }
      }
      __syncthreads();

      // ---- combine + gates (thread owns row rr, col j0+jj) ----
      float z[4];
      #pragma unroll
      for (int g = 0; g < 4; g++) {
        float s = zp[0][g][rr][jj] + zp[1][g][rr][jj]
                + zp[2][g][rr][jj] + zp[3][g][rr][jj];
        if (l > 0)
          s += zp[4][g][rr][jj] + zp[5][g][rr][jj]
             + zp[6][g][rr][jj] + zp[7][g][rr][jj] + bias4[g];
        else
          s += zv4[g];
        z[g] = s;
      }
      if (l == 0) {
        #pragma unroll
        for (int g = 0; g < 4; g++) zv4[g] = zn4[g];
      }
      float ig = sigmoidf_(z[0]), fg = sigmoidf_(z[1]);
      float gv = tanhf(z[2]),     og = sigmoidf_(z[3]);
      cc = fg * cc + ig * gv;
      float hv = og * tanhf(cc);
      ushort hb = f2bf(hv);
      // chunked publish: even-jj threads store packed 4B (full-line pattern)
      unsigned u = (unsigned)hb;
      unsigned nb = __shfl_xor(u, 1);
      if ((jj & 1) == 0)
        st4_sys(hxC + ((size_t)l * 2 + (t & 1)) * 32768 + jg * 512 + rr * 16 + jj,
                u | (nb << 16));
      if (t == TLEN - 1) {
        hS [(size_t)l * 32768 + rr * HID + j0 + jj] = hb;
        cSe[(size_t)l * 32768 + rr * HID + j0 + jj] = cc;
      }
      wait_vm0();
    }
    __syncthreads();
    if (tid == 0) st4_sys(flags + bx * 4, (unsigned)(w + 1));
  }
}

// --- decoder per-layer persistent recurrence --------------------------------
// Flags monotonic across layers: layer l uses fbase = l*TLEN; h0 for layers
// 1,2 is already in the correct parity slot (prev layer's last publish).
__global__ __launch_bounds__(256, 1) void lstm_seq(
    const float*  __restrict__ Zpre,   // [TLEN][32][4096] (incl bias)
    const ushort* __restrict__ Wht,    // [4096][1024]
    float*        __restrict__ cS,     // [32][1024] c state in/out
    ushort*       __restrict__ yout,   // [TLEN][32][1024] linear out
    ushort*       __restrict__ hx,     // [2][64][32][16] chunked exchange
    unsigned*     __restrict__ flags,  // 64 flags, stride 4 dwords
    unsigned fbase)
{
  const int jg = blockIdx.x;
  const int j0 = jg * 16;
  const int tid = threadIdx.x;
  const int lane = tid & 63, wave = tid >> 6;
  const int rr = tid >> 3, cp = tid & 7;

  __shared__ float zp[4][4][32][17];   // [k-slice wave][gate][row][col+pad]

  float2 cc = *(const float2*)(cS + (size_t)rr * HID + j0 + 2 * cp);

  bf8 bw[4][8];
  #pragma unroll
  for (int g = 0; g < 4; g++) {
    const ushort* Bp = Wht + (size_t)(g * HID + j0 + (lane & 15)) * HID
                     + wave * 256 + (lane >> 4) * 8;
    #pragma unroll
    for (int kk = 0; kk < 8; kk++)
      bw[g][kk] = *(const bf8*)(Bp + kk * 32);
  }

  const int r0 = lane & 15, r1 = r0 + 16;
  const int lk = lane >> 4;
  const int aoff0 = wave * 8192 + (lk >> 1) * 512 + r0 * 16 + (lk & 1) * 8;
  const int aoff1 = wave * 8192 + (lk >> 1) * 512 + r1 * 16 + (lk & 1) * 8;

  float2 zv[4], zn[4];
  #pragma unroll
  for (int g = 0; g < 4; g++)
    zv[g] = *(const float2*)(Zpre + (size_t)rr * G4 + g * HID + j0 + 2 * cp);

  for (int t = 0; t < TLEN; ++t) {
    // all 4 waves poll independently; no barrier afterward (256 streams: ok)
    if (t > 0) {
      const unsigned* fp = flags + lane * 4;
      const unsigned want = fbase + (unsigned)t;
      while (__ballot(ld4_sys(fp) < want)) {}
    }
    const ushort* hsrc = hx + ((t + 1) & 1) * 32768;
    uint4 ha0[8], ha1[8];
    #pragma unroll
    for (int kk = 0; kk < 8; kk++) {
      ld16_sys(ha0[kk], hsrc + aoff0 + kk * 1024);
      ld16_sys(ha1[kk], hsrc + aoff1 + kk * 1024);
    }
    wait_vm0();

    if (t + 1 < TLEN) {
      const float* Ztn = Zpre + (size_t)(t + 1) * 32 * G4;
      #pragma unroll
      for (int g = 0; g < 4; g++)
        zn[g] = *(const float2*)(Ztn + (size_t)rr * G4 + g * HID + j0 + 2 * cp);
    }

    f4 acc0[4], acc1[4];
    #pragma unroll
    for (int g = 0; g < 4; g++) { acc0[g] = (f4){0,0,0,0}; acc1[g] = (f4){0,0,0,0}; }
    #pragma unroll
    for (int kk = 0; kk < 8; kk++) {
      bf8 a0 = __builtin_bit_cast(bf8, ha0[kk]);
      bf8 a1 = __builtin_bit_cast(bf8, ha1[kk]);
      #pragma unroll
      for (int g = 0; g < 4; g++) {
        acc0[g] = __builtin_amdgcn_mfma_f32_16x16x32_bf16(a0, bw[g][kk], acc0[g], 0, 0, 0);
        acc1[g] = __builtin_amdgcn_mfma_f32_16x16x32_bf16(a1, bw[g][kk], acc1[g], 0, 0, 0);
      }
    }
    #pragma unroll
    for (int g = 0; g < 4; g++)
      #pragma unroll
      for (int v = 0; v < 4; v++) {
        zp[wave][g][(lane >> 4) * 4 + v][lane & 15]      = acc0[g][v];
        zp[wave][g][16 + (lane >> 4) * 4 + v][lane & 15] = acc1[g][v];
      }
    __syncthreads();

    float zx[4], zy[4];
    #pragma unroll
    for (int g = 0; g < 4; g++) {
      zx[g] = zv[g].x + zp[0][g][rr][2 * cp]     + zp[1][g][rr][2 * cp]
                      + zp[2][g][rr][2 * cp]     + zp[3][g][rr][2 * cp];
      zy[g] = zv[g].y + zp[0][g][rr][2 * cp + 1] + zp[1][g][rr][2 * cp + 1]
                      + zp[2][g][rr][2 * cp + 1] + zp[3][g][rr][2 * cp + 1];
    }
    cc.x = sigmoidf_(zx[1]) * cc.x + sigmoidf_(zx[0]) * tanhf(zx[2]);
    cc.y = sigmoidf_(zy[1]) * cc.y + sigmoidf_(zy[0]) * tanhf(zy[2]);
    float hv0 = sigmoidf_(zx[3]) * tanhf(cc.x);
    float hv1 = sigmoidf_(zy[3]) * tanhf(cc.y);
    unsigned packed = (unsigned)f2bf(hv0) | ((unsigned)f2bf(hv1) << 16);
    *(unsigned*)(yout + (size_t)t * 32768 + rr * HID + j0 + 2 * cp) = packed;
    st4_sys(hx + (size_t)(t & 1) * 32768 + jg * 512 + rr * 16 + 2 * cp, packed);
    #pragma unroll
    for (int g = 0; g < 4; g++) zv[g] = zn[g];

    wait_vm0();
    __syncthreads();
    if (tid == 0) st4_sys(flags + jg * 4, fbase + (unsigned)(t + 1));
  }
  *(float2*)(cS + (size_t)rr * HID + j0 + 2 * cp) = cc;
}

// --- prep kernels -----------------------------------------------------------
__global__ __launch_bounds__(256) void prep_enc(ushort* hxC, float* cSe,
                                                unsigned* flags) {
  int i = blockIdx.x * 256 + threadIdx.x;      // 768 blocks * 256 = 196608
  hxC[i] = 0;
  if (i < 98304) cSe[i] = 0.f;
  if (i < 192)   flags[i * 4] = 0;
}
// enc final state -> chunk layout into hx[1]; c copy; flags zeroed (once)
__global__ __launch_bounds__(256) void prep_dec0(const ushort* __restrict__ hS2,
                                                 const float* __restrict__ cSe2,
                                                 float* cS, ushort* hx,
                                                 unsigned* flags) {
  int i = blockIdx.x * 256 + threadIdx.x;      // 128 blocks * 256 = 32768
  int row = i >> 10, col = i & 1023;
  hx[32768 + (col >> 4) * 512 + row * 16 + (col & 15)] = hS2[i];
  cS[i] = cSe2[i];
  if (i < NBLK_SEQ) flags[i * 4] = 0;
}

// ---------------------------------------------------------------------------
extern "C" void kernel_launch(void* const* d_in, const int* in_sizes, int n_in,
                              void* d_out, int out_size, void* d_ws, size_t ws_size,
                              hipStream_t stream) {
  const int*   enc_ids = (const int*)d_in[0];
  const int*   dec_ids = (const int*)d_in[1];
  const float* emb     = (const float*)d_in[2];
  const float* Wx_enc  = (const float*)d_in[3];
  const float* Wh_enc  = (const float*)d_in[4];
  const float* b_enc   = (const float*)d_in[5];
  const float* Wx_dec  = (const float*)d_in[6];
  const float* Wh_dec  = (const float*)d_in[7];
  const float* b_dec   = (const float*)d_in[8];
  const float* dense_W = (const float*)d_in[9];
  const float* dense_b = (const float*)d_in[10];
  float* out = (float*)d_out;

  // ---- d_ws layout (proven footprint) ----
  char* ws = (char*)d_ws;
  const size_t SZ_BUF = (size_t)4096 * 1024 * 2;   // 8 MiB
  ushort*   bufA   = (ushort*)(ws);
  ushort*   bufB   = (ushort*)(ws + SZ_BUF);
  ushort*   Wxt    = (ushort*)(ws + 2 * SZ_BUF);
  ushort*   Wht    = (ushort*)(ws + 3 * SZ_BUF);
  ushort*   dWt    = (ushort*)(ws + 4 * SZ_BUF);   // VOC*1024*2 B
  char*     p2     = ws + 4 * SZ_BUF + (size_t)VOC * 1024 * 2;
  float*    cS     = (float*)(p2 + (size_t)32 * 1024 * 2);   // 128 KiB
  unsigned* flags  = (unsigned*)(p2 + (size_t)32 * 1024 * 2 + (size_t)32 * 1024 * 4);

  // ---- d_out dead-region scratch (500 MB buffer, dense head writes last) --
  char* ob = (char*)d_out;
  float*    Zpre   = out;                                        // [0, 64 MiB)
  ushort*   WhTe   = (ushort*)(ob + (size_t)64  * 1024 * 1024);  // 3 x 8 MiB
  ushort*   WxTe   = (ushort*)(ob + (size_t)88  * 1024 * 1024);  // 2 x 8 MiB
  char*     st     = ob + (size_t)112 * 1024 * 1024;
  ushort*   hxC    = (ushort*)st;                                // 384 KiB chunked
  float*    cSe    = (float*)(st + 393216);                      // 384 KiB
  ushort*   hS     = (ushort*)(st + 786432);                     // 192 KiB
  unsigned* flags2 = (unsigned*)(st + 983040);                   // 3 KiB
  ushort*   hxD    = (ushort*)(ob + (size_t)120 * 1024 * 1024);  // 128 KiB chunked
  const size_t WSTRIDE = (size_t)G4 * HID;                       // elements

  transpose_cvt<<<dim3(VOC / 32, 1024 / 32), 256, 0, stream>>>(dense_W, dWt, 1024, VOC);

  // ---------------- encoder ----------------
  embed_kernel<<<4096, 256, 0, stream>>>(enc_ids, emb, bufA);
  transpose_cvt<<<dim3(G4 / 32, 32), 256, 0, stream>>>(Wx_enc, Wxt, 1024, G4);
  gemm_bt<<<dim3(G4 / 128, 4096 / 128), 256, 0, stream>>>(bufA, Wxt, b_enc,
                                                          Zpre, 4096, G4, 1024, 0);
  for (int l = 0; l < 3; l++)
    transpose_cvt<<<dim3(G4 / 32, 32), 256, 0, stream>>>(Wh_enc + (size_t)l * 1024 * G4,
                                                         WhTe + l * WSTRIDE, 1024, G4);
  for (int l = 1; l < 3; l++)
    transpose_cvt<<<dim3(G4 / 32, 32), 256, 0, stream>>>(Wx_enc + (size_t)l * 1024 * G4,
                                                         WxTe + (l - 1) * WSTRIDE, 1024, G4);
  prep_enc<<<768, 256, 0, stream>>>(hxC, cSe, flags2);
  enc_wave<<<192, 512, 0, stream>>>(Zpre, WhTe, WxTe, b_enc, hxC, cSe, hS, flags2);

  // ---------------- decoder (serial chaining -> per-layer) ----------------
  embed_kernel<<<4096, 256, 0, stream>>>(dec_ids, emb, bufA);
  ushort* cur = bufA; ushort* oth = bufB;
  for (int l = 0; l < 3; l++) {
    transpose_cvt<<<dim3(G4 / 32, 32), 256, 0, stream>>>(Wx_dec + (size_t)l * 1024 * G4, Wxt, 1024, G4);
    transpose_cvt<<<dim3(G4 / 32, 32), 256, 0, stream>>>(Wh_dec + (size_t)l * 1024 * G4, Wht, 1024, G4);
    gemm_bt<<<dim3(G4 / 128, 4096 / 128), 256, 0, stream>>>(cur, Wxt, b_dec + (size_t)l * G4,
                                                            Zpre, 4096, G4, 1024, 0);
    if (l == 0)
      prep_dec0<<<128, 256, 0, stream>>>(hS + 2 * 32768, cSe + 2 * 32768, cS, hxD, flags);
    // layers 1,2: h0 already in hxD parity-1 slot; c chains in cS; flags continue
    lstm_seq<<<NBLK_SEQ, 256, 0, stream>>>(Zpre, Wht, cS, oth, hxD, flags,
                                           (unsigned)(l * TLEN));
    ushort* tmp = cur; cur = oth; oth = tmp;
  }

  // ---------------- dense head: logits[b][t][v] ----------------
  gemm_bt<<<dim3(VOC / 128, 4096 / 128), 256, 0, stream>>>(cur, dWt, dense_b, out,
                                                           4096, VOC, 1024, 1);
}